// Round 10
// baseline (107.603 us; speedup 1.0000x reference)
//
#include <hip/hip_runtime.h>
#include <math.h>

// Problem constants
constexpr int B_  = 2;
constexpr int Q_  = 2048;
constexpr int D_  = 1024;
constexpr int H_  = 16;
constexpr int R_  = 12;
constexpr int DH_ = 64;
constexpr int M_  = B_ * Q_;     // 4096
constexpr int HR_ = H_ * R_;     // 192
constexpr int NQKV = 3 * D_;     // 3072

typedef short bf16x8 __attribute__((ext_vector_type(8)));
typedef float f32x4  __attribute__((ext_vector_type(4)));

__device__ __forceinline__ float bf2f(unsigned short u) {
    return __uint_as_float(((unsigned)u) << 16);
}
__device__ __forceinline__ unsigned short f2bf(float f) {
    unsigned u = __float_as_uint(f);
    return (unsigned short)((u + 0x7fffu + ((u >> 16) & 1u)) >> 16);
}

// ---------------------------------------------------------------------------
// One merged conversion kernel: x|wq|wk|wv|wo|pww fp32->bf16 (+ bias concat).
// ---------------------------------------------------------------------------
__global__ __launch_bounds__(256) void cvt_all(const float* __restrict__ x,
                                               const float* __restrict__ wq,
                                               const float* __restrict__ wk,
                                               const float* __restrict__ wv,
                                               const float* __restrict__ wo,
                                               const float* __restrict__ pww,
                                               const float* __restrict__ bq,
                                               const float* __restrict__ bk,
                                               const float* __restrict__ bv,
                                               unsigned short* __restrict__ xb,
                                               unsigned short* __restrict__ wqkv,
                                               unsigned short* __restrict__ wob,
                                               unsigned short* __restrict__ pwwb,
                                               float* __restrict__ bqkv) {
    const int blk = blockIdx.x;
    if (blk >= 4192) {  // bias concat: 12 blocks x 256 = 3072
        const int i = (blk - 4192) * 256 + threadIdx.x;
        bqkv[i] = i < D_ ? bq[i] : (i < 2 * D_ ? bk[i - D_] : bv[i - 2 * D_]);
        return;
    }
    const int i = blk * 256 + threadIdx.x;  // 8-element unit index
    const float* src;
    unsigned short* dst;
    int rel;
    if (i < 524288)       { src = x;   dst = xb;                          rel = i; }
    else if (i < 655360)  { src = wq;  dst = wqkv;                        rel = i - 524288; }
    else if (i < 786432)  { src = wk;  dst = wqkv + (size_t)D_ * D_;      rel = i - 655360; }
    else if (i < 917504)  { src = wv;  dst = wqkv + (size_t)2 * D_ * D_;  rel = i - 786432; }
    else if (i < 1048576) { src = wo;  dst = wob;                         rel = i - 917504; }
    else                  { src = pww; dst = pwwb;                        rel = i - 1048576; }

    const float4 a = ((const float4*)src)[2 * rel];
    const float4 b = ((const float4*)src)[2 * rel + 1];
    uint4 o;
    o.x = (unsigned)f2bf(a.x) | ((unsigned)f2bf(a.y) << 16);
    o.y = (unsigned)f2bf(a.z) | ((unsigned)f2bf(a.w) << 16);
    o.z = (unsigned)f2bf(b.x) | ((unsigned)f2bf(b.y) << 16);
    o.w = (unsigned)f2bf(b.z) | ((unsigned)f2bf(b.w) << 16);
    ((uint4*)dst)[rel] = o;
}

// ---------------------------------------------------------------------------
// bf16 MFMA GEMM (m97 single-buffer structure), BK=64, both-sides 16B-slot
// XOR swizzle, column-grouped XCD mapping. C-writes are NON-TEMPORAL: rocprof
// showed 40MB FETCH vs 14 compulsory on QKV = write-allocate traffic; nt
// avoids the RFO and skips useless L2 retention (outputs are L3-consumed).
// ---------------------------------------------------------------------------
template <int BN, bool OUT_BF16>
__global__ __launch_bounds__(256) void gemm_mfma(const unsigned short* __restrict__ A,
                                                 const unsigned short* __restrict__ W,
                                                 const float* __restrict__ bias,
                                                 void* __restrict__ Cv,
                                                 int M, int N, int K) {
    constexpr int BM  = 128, BK = 64;
    constexpr int FN  = BN / 32;
    constexpr int CHA = BM / 8;
    constexpr int CHB = BN / 8;
    __shared__ unsigned short As[BM * BK];
    __shared__ unsigned short Bs[BN * BK];

    const int tid  = threadIdx.x;
    const int w    = tid >> 6, lane = tid & 63;
    const int wm   = w >> 1,   wn   = w & 1;

    // column-grouped XCD swizzle (gridDim.x % 8 == 0)
    const int nbx = gridDim.x;
    const int cpx = nbx >> 3;
    const int orig = blockIdx.y * nbx + blockIdx.x;
    const int xcd  = orig & 7;
    const int idx  = orig >> 3;
    const int bm = (idx / cpx) * BM;
    const int bn = (xcd * cpx + idx % cpx) * BN;

    const int srow  = lane >> 3;
    const int sslot = (lane & 7) ^ (srow & 7);
    const int fr = lane & 15;
    const int s  = lane >> 4;
    const int fx = fr & 7;

    f32x4 acc[4][FN];
    #pragma unroll
    for (int i = 0; i < 4; ++i)
        #pragma unroll
        for (int j = 0; j < FN; ++j) acc[i][j] = (f32x4){0.f, 0.f, 0.f, 0.f};

    for (int k0 = 0; k0 < K; k0 += BK) {
        __syncthreads();
        #pragma unroll
        for (int c = w; c < CHA; c += 4) {
            const unsigned short* g = A + (size_t)(bm + c * 8 + srow) * K + k0 + sslot * 8;
            __builtin_amdgcn_global_load_lds(
                (const __attribute__((address_space(1))) void*)g,
                (__attribute__((address_space(3))) void*)((char*)As + c * 1024), 16, 0, 0);
        }
        #pragma unroll
        for (int c = w; c < CHB; c += 4) {
            const unsigned short* g = W + (size_t)(bn + c * 8 + srow) * K + k0 + sslot * 8;
            __builtin_amdgcn_global_load_lds(
                (const __attribute__((address_space(1))) void*)g,
                (__attribute__((address_space(3))) void*)((char*)Bs + c * 1024), 16, 0, 0);
        }
        __syncthreads();

        #pragma unroll
        for (int ks = 0; ks < 2; ++ks) {
            const int sl = (((ks << 2) | s) ^ fx) * 8;
            bf16x8 af[4];
            #pragma unroll
            for (int i = 0; i < 4; ++i)
                af[i] = *(const bf16x8*)(As + (wm * 64 + i * 16 + fr) * BK + sl);
            #pragma unroll
            for (int j = 0; j < FN; ++j) {
                const bf16x8 bfrag = *(const bf16x8*)(Bs + (wn * (BN / 2) + j * 16 + fr) * BK + sl);
                #pragma unroll
                for (int i = 0; i < 4; ++i)
                    acc[i][j] = __builtin_amdgcn_mfma_f32_16x16x32_bf16(af[i], bfrag, acc[i][j], 0, 0, 0);
            }
        }
    }

    #pragma unroll
    for (int j = 0; j < FN; ++j) {
        const int col = bn + wn * (BN / 2) + j * 16 + fr;
        const float bv = bias[col];
        #pragma unroll
        for (int i = 0; i < 4; ++i) {
            const int row0 = bm + wm * 64 + i * 16 + ((lane >> 4) << 2);
            #pragma unroll
            for (int ii = 0; ii < 4; ++ii) {
                const float v = acc[i][j][ii] + bv;
                if constexpr (OUT_BF16)
                    __builtin_nontemporal_store(f2bf(v),
                        (unsigned short*)Cv + (size_t)(row0 + ii) * N + col);
                else
                    __builtin_nontemporal_store(v,
                        (float*)Cv + (size_t)(row0 + ii) * N + col);
            }
        }
    }
}

// ---------------------------------------------------------------------------
// Fused depthwise-conv1d(k=3)+GELU + pointwise GEMM (N=192).
// ---------------------------------------------------------------------------
__global__ __launch_bounds__(256) void dwpw_kernel(const unsigned short* __restrict__ qkv,
                                                   const float* __restrict__ dww,
                                                   const float* __restrict__ dwb,
                                                   const unsigned short* __restrict__ pwwb,
                                                   const float* __restrict__ pwb,
                                                   unsigned short* __restrict__ offb) {
    __shared__ unsigned short As[16 * 1024];
    __shared__ unsigned short Bs[192 * 64];
    const int tid  = threadIdx.x;
    const int w    = tid >> 6, lane = tid & 63;
    const int m0   = blockIdx.x * 16;

    for (int u = tid; u < 16 * 128; u += 256) {
        const int r  = u >> 7;
        const int c8 = (u & 127) << 3;
        const int m  = m0 + r;
        const int t  = m & (Q_ - 1);
        const unsigned short* row = qkv + (size_t)m * NQKV + c8;

        unsigned short cur[8], prv[8] = {0}, nxt[8] = {0};
        *(uint4*)cur = *(const uint4*)row;
        if (t > 0)      *(uint4*)prv = *(const uint4*)(row - NQKV);
        if (t < Q_ - 1) *(uint4*)nxt = *(const uint4*)(row + NQKV);

        float dwl[24];
        #pragma unroll
        for (int q2 = 0; q2 < 6; ++q2)
            *(f32x4*)&dwl[q2 * 4] = *(const f32x4*)&dww[c8 * 3 + q2 * 4];
        float db[8];
        *(f32x4*)&db[0] = *(const f32x4*)&dwb[c8];
        *(f32x4*)&db[4] = *(const f32x4*)&dwb[c8 + 4];

        unsigned short o[8];
        #pragma unroll
        for (int j = 0; j < 8; ++j) {
            float v = bf2f(prv[j]) * dwl[j * 3 + 0] + bf2f(cur[j]) * dwl[j * 3 + 1]
                    + bf2f(nxt[j]) * dwl[j * 3 + 2] + db[j];
            v = 0.5f * v * (1.0f + erff(v * 0.70710678118654752f));
            o[j] = f2bf(v);
        }
        const int slot = (c8 >> 3) ^ (r & 7);
        *(uint4*)(As + r * 1024 + slot * 8) = *(uint4*)o;
    }
    __syncthreads();

    const int srow  = lane >> 3;
    const int sslot = (lane & 7) ^ (srow & 7);
    const int fr = lane & 15;
    const int s  = lane >> 4;
    const int fx = fr & 7;

    f32x4 acc[3];
    #pragma unroll
    for (int j = 0; j < 3; ++j) acc[j] = (f32x4){0.f, 0.f, 0.f, 0.f};

    for (int k0 = 0; k0 < 1024; k0 += 64) {
        if (k0) __syncthreads();
        #pragma unroll
        for (int c = w; c < 24; c += 4) {
            const unsigned short* g = pwwb + (size_t)(c * 8 + srow) * 1024 + k0 + sslot * 8;
            __builtin_amdgcn_global_load_lds(
                (const __attribute__((address_space(1))) void*)g,
                (__attribute__((address_space(3))) void*)((char*)Bs + c * 1024), 16, 0, 0);
        }
        __syncthreads();

        #pragma unroll
        for (int ks = 0; ks < 2; ++ks) {
            const int aslot = ((k0 >> 3) + ((ks << 2) | s)) ^ fx;
            const bf16x8 af = *(const bf16x8*)(As + fr * 1024 + aslot * 8);
            const int sl = (((ks << 2) | s) ^ fx) * 8;
            #pragma unroll
            for (int j = 0; j < 3; ++j) {
                const bf16x8 bfrag = *(const bf16x8*)(Bs + (w * 48 + j * 16 + fr) * 64 + sl);
                acc[j] = __builtin_amdgcn_mfma_f32_16x16x32_bf16(af, bfrag, acc[j], 0, 0, 0);
            }
        }
    }

    #pragma unroll
    for (int j = 0; j < 3; ++j) {
        const int n = w * 48 + j * 16 + fr;
        const float bv = pwb[n];
        const int row0 = (lane >> 4) << 2;
        #pragma unroll
        for (int ii = 0; ii < 4; ++ii)
            offb[(size_t)(m0 + row0 + ii) * HR_ + n] = f2bf(acc[j][ii] + bv);
    }
}

// ---------------------------------------------------------------------------
// Fused banded-score + softmax + band coefficients + PV.
// ---------------------------------------------------------------------------
__global__ __launch_bounds__(256) void coeff_pv_kernel(const unsigned short* __restrict__ qkv,
                                                       const unsigned short* __restrict__ offb,
                                                       const float* __restrict__ rel_scale_p,
                                                       unsigned short* __restrict__ attb) {
    __shared__ __align__(16) float S[4][16][33];
    __shared__ __align__(16) float C[4][16][32];
    const int tid  = threadIdx.x;
    const int w    = tid >> 6, lane = tid & 63;
    const int tile = blockIdx.x * 4 + w;
    const int t0   = (tile & 127) << 4;
    const int h    = (tile >> 7) & 15;
    const int b    = tile >> 11;
    const int fr   = lane & 15;
    const int fo   = (lane >> 4) << 3;

    const unsigned short* qrow = qkv + (size_t)(b * Q_ + t0 + fr) * NQKV + h * DH_ + fo;
    const bf16x8 af0 = *(const bf16x8*)qrow;
    const bf16x8 af1 = *(const bf16x8*)(qrow + 32);

    f32x4 acc0 = (f32x4){0.f, 0.f, 0.f, 0.f};
    f32x4 acc1 = acc0;
    {
        int j = min(max(t0 - 8 + fr, 0), Q_ - 1);
        const unsigned short* krow = qkv + (size_t)(b * Q_ + j) * NQKV + D_ + h * DH_ + fo;
        acc0 = __builtin_amdgcn_mfma_f32_16x16x32_bf16(af0, *(const bf16x8*)krow, acc0, 0, 0, 0);
        acc0 = __builtin_amdgcn_mfma_f32_16x16x32_bf16(af1, *(const bf16x8*)(krow + 32), acc0, 0, 0, 0);
    }
    {
        int j = min(max(t0 + 8 + fr, 0), Q_ - 1);
        const unsigned short* krow = qkv + (size_t)(b * Q_ + j) * NQKV + D_ + h * DH_ + fo;
        acc1 = __builtin_amdgcn_mfma_f32_16x16x32_bf16(af0, *(const bf16x8*)krow, acc1, 0, 0, 0);
        acc1 = __builtin_amdgcn_mfma_f32_16x16x32_bf16(af1, *(const bf16x8*)(krow + 32), acc1, 0, 0, 0);
    }

    float vj[32];
    {
        const unsigned short* vb = qkv + (size_t)b * Q_ * NQKV + 2 * D_ + h * DH_ + lane;
        #pragma unroll
        for (int i2 = 0; i2 < 32; ++i2) {
            const int j = min(max(t0 - 8 + i2, 0), Q_ - 1);
            vj[i2] = bf2f(vb[(size_t)j * NQKV]);
        }
    }

    const int row0 = (lane >> 4) << 2;
    #pragma unroll
    for (int ii = 0; ii < 4; ++ii) {
        S[w][row0 + ii][fr]      = acc0[ii];
        S[w][row0 + ii][16 + fr] = acc1[ii];
    }
    {
        const int tr = lane >> 2, cg = (lane & 3) << 3;
        #pragma unroll
        for (int k = 0; k < 8; ++k) C[w][tr][cg + k] = 0.f;
    }
    __syncthreads();

    const int tloc = lane & 15;
    const int rs   = lane >> 4;
    const int t    = t0 + tloc;
    const float rel_scale = rel_scale_p[0];
    const unsigned short* offrow = offb + (size_t)(b * Q_ + t) * HR_ + h * R_;

    float sc[3], fr3[3];
    int   cl[3], ch[3];
    #pragma unroll
    for (int i = 0; i < 3; ++i) {
        const int r = rs * 3 + i;
        const float off    = bf2f(offrow[r]);
        const float anchor = -2.0f + (4.0f / 11.0f) * (float)r;
        float pos = (float)t + anchor + 6.0f * tanhf(off);
        pos = fminf(fmaxf(pos, 0.0f), (float)(Q_ - 1));
        const float fl = floorf(pos);
        const int lo = (int)fl;
        const int hi = (int)ceilf(pos);
        const float f = pos - fl;
        cl[i] = lo - t0 + 8;
        ch[i] = hi - t0 + 8;
        fr3[i] = f;
        const float slo = S[w][tloc][cl[i]];
        const float shi = S[w][tloc][ch[i]];
        sc[i] = (slo * (1.0f - f) + shi * f) * 0.125f - rel_scale * fabsf(pos - (float)t);
    }

    float mx = fmaxf(fmaxf(sc[0], sc[1]), sc[2]);
    mx = fmaxf(mx, __shfl_xor(mx, 16));
    mx = fmaxf(mx, __shfl_xor(mx, 32));
    float e[3];
    #pragma unroll
    for (int i = 0; i < 3; ++i) e[i] = expf(sc[i] - mx);
    float sum = e[0] + e[1] + e[2];
    sum += __shfl_xor(sum, 16);
    sum += __shfl_xor(sum, 32);
    const float inv = 1.0f / sum;

    #pragma unroll
    for (int i = 0; i < 3; ++i) {
        const float wgt = e[i] * inv;
        atomicAdd(&C[w][tloc][cl[i]], wgt * (1.0f - fr3[i]));
        atomicAdd(&C[w][tloc][ch[i]], wgt * fr3[i]);
    }
    __syncthreads();

    #pragma unroll
    for (int tl = 0; tl < 16; ++tl) {
        const int st = tl & ~3;
        float cw[20];
        #pragma unroll
        for (int q2 = 0; q2 < 5; ++q2)
            *(f32x4*)&cw[q2 * 4] = *(const f32x4*)&C[w][tl][st + q2 * 4];
        float acc2 = 0.f;
        #pragma unroll
        for (int k = 0; k <= 16; ++k)
            acc2 = fmaf(cw[tl - st + k], vj[tl + k], acc2);
        attb[(size_t)(b * Q_ + t0 + tl) * D_ + h * DH_ + lane] = f2bf(acc2);
    }
}

// ---------------------------------------------------------------------------
// Launch
// ---------------------------------------------------------------------------
extern "C" void kernel_launch(void* const* d_in, const int* in_sizes, int n_in,
                              void* d_out, int out_size, void* d_ws, size_t ws_size,
                              hipStream_t stream) {
    const float* x    = (const float*)d_in[0];
    const float* wq   = (const float*)d_in[1];
    const float* bq   = (const float*)d_in[2];
    const float* wk   = (const float*)d_in[3];
    const float* bk   = (const float*)d_in[4];
    const float* wv   = (const float*)d_in[5];
    const float* bv   = (const float*)d_in[6];
    const float* wo   = (const float*)d_in[7];
    const float* bo   = (const float*)d_in[8];
    const float* dww  = (const float*)d_in[9];
    const float* dwb  = (const float*)d_in[10];
    const float* pww  = (const float*)d_in[11];
    const float* pwb  = (const float*)d_in[12];
    const float* rsc  = (const float*)d_in[13];
    float* out = (float*)d_out;

    unsigned short* xb   = (unsigned short*)d_ws;              // M_*D_
    unsigned short* wqkv = xb   + (size_t)M_ * D_;             // NQKV*D_
    unsigned short* wob  = wqkv + (size_t)NQKV * D_;           // D_*D_
    unsigned short* pwwb = wob  + (size_t)D_ * D_;             // HR_*D_
    unsigned short* qkv  = pwwb + (size_t)HR_ * D_;            // M_*NQKV
    unsigned short* offb = qkv  + (size_t)M_ * NQKV;           // M_*HR_
    unsigned short* attb = offb + (size_t)M_ * HR_;            // M_*D_
    float*          bqkv = (float*)(attb + (size_t)M_ * D_);   // NQKV

    dim3 blk(256);

    hipLaunchKernelGGL(cvt_all, dim3(4204), blk, 0, stream,
                       x, wq, wk, wv, wo, pww, bq, bk, bv, xb, wqkv, wob, pwwb, bqkv);

    // fused QKV projection: (4096 x 1024) @ (3072 x 1024)^T, 768 blocks
    hipLaunchKernelGGL((gemm_mfma<128, true>), dim3(NQKV / 128, M_ / 128), blk, 0, stream,
                       xb, wqkv, bqkv, qkv, M_, NQKV, D_);

    // fused depthwise conv + gelu + pointwise conv -> raw offsets
    hipLaunchKernelGGL(dwpw_kernel, dim3(M_ / 16), blk, 0, stream,
                       qkv, dww, dwb, pwwb, pwb, offb);

    // banded score + softmax + coefficients + PV (fused)
    hipLaunchKernelGGL(coeff_pv_kernel, dim3(B_ * H_ * (Q_ / 16) / 4), blk, 0, stream,
                       qkv, offb, rsc, attb);

    // output projection -> fp32 d_out (512 blocks)
    hipLaunchKernelGGL((gemm_mfma<64, false>), dim3(D_ / 64, M_ / 128), blk, 0, stream,
                       attb, wob, bo, out, M_, D_, D_);
}

// Round 11
// 97.744 us; speedup vs baseline: 1.1009x; 1.1009x over previous
//
#include <hip/hip_runtime.h>
#include <math.h>

// Problem constants
constexpr int B_  = 2;
constexpr int Q_  = 2048;
constexpr int D_  = 1024;
constexpr int H_  = 16;
constexpr int R_  = 12;
constexpr int DH_ = 64;
constexpr int M_  = B_ * Q_;     // 4096
constexpr int HR_ = H_ * R_;     // 192
constexpr int NQKV = 3 * D_;     // 3072

typedef short bf16x8 __attribute__((ext_vector_type(8)));
typedef float f32x4  __attribute__((ext_vector_type(4)));

__device__ __forceinline__ float bf2f(unsigned short u) {
    return __uint_as_float(((unsigned)u) << 16);
}
__device__ __forceinline__ unsigned short f2bf(float f) {
    unsigned u = __float_as_uint(f);
    return (unsigned short)((u + 0x7fffu + ((u >> 16) & 1u)) >> 16);
}

// ---------------------------------------------------------------------------
// One merged conversion kernel: x|wq|wk|wv|wo|pww fp32->bf16 (+ bias concat).
// ---------------------------------------------------------------------------
__global__ __launch_bounds__(256) void cvt_all(const float* __restrict__ x,
                                               const float* __restrict__ wq,
                                               const float* __restrict__ wk,
                                               const float* __restrict__ wv,
                                               const float* __restrict__ wo,
                                               const float* __restrict__ pww,
                                               const float* __restrict__ bq,
                                               const float* __restrict__ bk,
                                               const float* __restrict__ bv,
                                               unsigned short* __restrict__ xb,
                                               unsigned short* __restrict__ wqkv,
                                               unsigned short* __restrict__ wob,
                                               unsigned short* __restrict__ pwwb,
                                               float* __restrict__ bqkv) {
    const int blk = blockIdx.x;
    if (blk >= 4192) {  // bias concat: 12 blocks x 256 = 3072
        const int i = (blk - 4192) * 256 + threadIdx.x;
        bqkv[i] = i < D_ ? bq[i] : (i < 2 * D_ ? bk[i - D_] : bv[i - 2 * D_]);
        return;
    }
    const int i = blk * 256 + threadIdx.x;  // 8-element unit index
    const float* src;
    unsigned short* dst;
    int rel;
    if (i < 524288)       { src = x;   dst = xb;                          rel = i; }
    else if (i < 655360)  { src = wq;  dst = wqkv;                        rel = i - 524288; }
    else if (i < 786432)  { src = wk;  dst = wqkv + (size_t)D_ * D_;      rel = i - 655360; }
    else if (i < 917504)  { src = wv;  dst = wqkv + (size_t)2 * D_ * D_;  rel = i - 786432; }
    else if (i < 1048576) { src = wo;  dst = wob;                         rel = i - 917504; }
    else                  { src = pww; dst = pwwb;                        rel = i - 1048576; }

    const float4 a = ((const float4*)src)[2 * rel];
    const float4 b = ((const float4*)src)[2 * rel + 1];
    uint4 o;
    o.x = (unsigned)f2bf(a.x) | ((unsigned)f2bf(a.y) << 16);
    o.y = (unsigned)f2bf(a.z) | ((unsigned)f2bf(a.w) << 16);
    o.z = (unsigned)f2bf(b.x) | ((unsigned)f2bf(b.y) << 16);
    o.w = (unsigned)f2bf(b.z) | ((unsigned)f2bf(b.w) << 16);
    ((uint4*)dst)[rel] = o;
}

// ---------------------------------------------------------------------------
// bf16 MFMA GEMM (m97 single-buffer structure), BK=64, both-sides 16B-slot
// XOR swizzle, column-grouped XCD mapping. Plain cached stores (L2
// write-combining beats both LDS-transpose (R9) and nt-store (R10) variants).
// ---------------------------------------------------------------------------
template <int BN, bool OUT_BF16>
__global__ __launch_bounds__(256) void gemm_mfma(const unsigned short* __restrict__ A,
                                                 const unsigned short* __restrict__ W,
                                                 const float* __restrict__ bias,
                                                 void* __restrict__ Cv,
                                                 int M, int N, int K) {
    constexpr int BM  = 128, BK = 64;
    constexpr int FN  = BN / 32;
    constexpr int CHA = BM / 8;
    constexpr int CHB = BN / 8;
    __shared__ unsigned short As[BM * BK];
    __shared__ unsigned short Bs[BN * BK];

    const int tid  = threadIdx.x;
    const int w    = tid >> 6, lane = tid & 63;
    const int wm   = w >> 1,   wn   = w & 1;

    // column-grouped XCD swizzle (gridDim.x % 8 == 0)
    const int nbx = gridDim.x;
    const int cpx = nbx >> 3;
    const int orig = blockIdx.y * nbx + blockIdx.x;
    const int xcd  = orig & 7;
    const int idx  = orig >> 3;
    const int bm = (idx / cpx) * BM;
    const int bn = (xcd * cpx + idx % cpx) * BN;

    const int srow  = lane >> 3;
    const int sslot = (lane & 7) ^ (srow & 7);
    const int fr = lane & 15;
    const int s  = lane >> 4;
    const int fx = fr & 7;

    f32x4 acc[4][FN];
    #pragma unroll
    for (int i = 0; i < 4; ++i)
        #pragma unroll
        for (int j = 0; j < FN; ++j) acc[i][j] = (f32x4){0.f, 0.f, 0.f, 0.f};

    for (int k0 = 0; k0 < K; k0 += BK) {
        __syncthreads();
        #pragma unroll
        for (int c = w; c < CHA; c += 4) {
            const unsigned short* g = A + (size_t)(bm + c * 8 + srow) * K + k0 + sslot * 8;
            __builtin_amdgcn_global_load_lds(
                (const __attribute__((address_space(1))) void*)g,
                (__attribute__((address_space(3))) void*)((char*)As + c * 1024), 16, 0, 0);
        }
        #pragma unroll
        for (int c = w; c < CHB; c += 4) {
            const unsigned short* g = W + (size_t)(bn + c * 8 + srow) * K + k0 + sslot * 8;
            __builtin_amdgcn_global_load_lds(
                (const __attribute__((address_space(1))) void*)g,
                (__attribute__((address_space(3))) void*)((char*)Bs + c * 1024), 16, 0, 0);
        }
        __syncthreads();

        #pragma unroll
        for (int ks = 0; ks < 2; ++ks) {
            const int sl = (((ks << 2) | s) ^ fx) * 8;
            bf16x8 af[4];
            #pragma unroll
            for (int i = 0; i < 4; ++i)
                af[i] = *(const bf16x8*)(As + (wm * 64 + i * 16 + fr) * BK + sl);
            #pragma unroll
            for (int j = 0; j < FN; ++j) {
                const bf16x8 bfrag = *(const bf16x8*)(Bs + (wn * (BN / 2) + j * 16 + fr) * BK + sl);
                #pragma unroll
                for (int i = 0; i < 4; ++i)
                    acc[i][j] = __builtin_amdgcn_mfma_f32_16x16x32_bf16(af[i], bfrag, acc[i][j], 0, 0, 0);
            }
        }
    }

    #pragma unroll
    for (int j = 0; j < FN; ++j) {
        const int col = bn + wn * (BN / 2) + j * 16 + fr;
        const float bv = bias[col];
        #pragma unroll
        for (int i = 0; i < 4; ++i) {
            const int row0 = bm + wm * 64 + i * 16 + ((lane >> 4) << 2);
            #pragma unroll
            for (int ii = 0; ii < 4; ++ii) {
                const float v = acc[i][j][ii] + bv;
                if constexpr (OUT_BF16)
                    ((unsigned short*)Cv)[(size_t)(row0 + ii) * N + col] = f2bf(v);
                else
                    ((float*)Cv)[(size_t)(row0 + ii) * N + col] = v;
            }
        }
    }
}

// ---------------------------------------------------------------------------
// Fused depthwise-conv1d(k=3)+GELU + pointwise GEMM (N=192).
// ---------------------------------------------------------------------------
__global__ __launch_bounds__(256) void dwpw_kernel(const unsigned short* __restrict__ qkv,
                                                   const float* __restrict__ dww,
                                                   const float* __restrict__ dwb,
                                                   const unsigned short* __restrict__ pwwb,
                                                   const float* __restrict__ pwb,
                                                   unsigned short* __restrict__ offb) {
    __shared__ unsigned short As[16 * 1024];
    __shared__ unsigned short Bs[192 * 64];
    const int tid  = threadIdx.x;
    const int w    = tid >> 6, lane = tid & 63;
    const int m0   = blockIdx.x * 16;

    for (int u = tid; u < 16 * 128; u += 256) {
        const int r  = u >> 7;
        const int c8 = (u & 127) << 3;
        const int m  = m0 + r;
        const int t  = m & (Q_ - 1);
        const unsigned short* row = qkv + (size_t)m * NQKV + c8;

        unsigned short cur[8], prv[8] = {0}, nxt[8] = {0};
        *(uint4*)cur = *(const uint4*)row;
        if (t > 0)      *(uint4*)prv = *(const uint4*)(row - NQKV);
        if (t < Q_ - 1) *(uint4*)nxt = *(const uint4*)(row + NQKV);

        float dwl[24];
        #pragma unroll
        for (int q2 = 0; q2 < 6; ++q2)
            *(f32x4*)&dwl[q2 * 4] = *(const f32x4*)&dww[c8 * 3 + q2 * 4];
        float db[8];
        *(f32x4*)&db[0] = *(const f32x4*)&dwb[c8];
        *(f32x4*)&db[4] = *(const f32x4*)&dwb[c8 + 4];

        unsigned short o[8];
        #pragma unroll
        for (int j = 0; j < 8; ++j) {
            float v = bf2f(prv[j]) * dwl[j * 3 + 0] + bf2f(cur[j]) * dwl[j * 3 + 1]
                    + bf2f(nxt[j]) * dwl[j * 3 + 2] + db[j];
            v = 0.5f * v * (1.0f + erff(v * 0.70710678118654752f));
            o[j] = f2bf(v);
        }
        const int slot = (c8 >> 3) ^ (r & 7);
        *(uint4*)(As + r * 1024 + slot * 8) = *(uint4*)o;
    }
    __syncthreads();

    const int srow  = lane >> 3;
    const int sslot = (lane & 7) ^ (srow & 7);
    const int fr = lane & 15;
    const int s  = lane >> 4;
    const int fx = fr & 7;

    f32x4 acc[3];
    #pragma unroll
    for (int j = 0; j < 3; ++j) acc[j] = (f32x4){0.f, 0.f, 0.f, 0.f};

    for (int k0 = 0; k0 < 1024; k0 += 64) {
        if (k0) __syncthreads();
        #pragma unroll
        for (int c = w; c < 24; c += 4) {
            const unsigned short* g = pwwb + (size_t)(c * 8 + srow) * 1024 + k0 + sslot * 8;
            __builtin_amdgcn_global_load_lds(
                (const __attribute__((address_space(1))) void*)g,
                (__attribute__((address_space(3))) void*)((char*)Bs + c * 1024), 16, 0, 0);
        }
        __syncthreads();

        #pragma unroll
        for (int ks = 0; ks < 2; ++ks) {
            const int aslot = ((k0 >> 3) + ((ks << 2) | s)) ^ fx;
            const bf16x8 af = *(const bf16x8*)(As + fr * 1024 + aslot * 8);
            const int sl = (((ks << 2) | s) ^ fx) * 8;
            #pragma unroll
            for (int j = 0; j < 3; ++j) {
                const bf16x8 bfrag = *(const bf16x8*)(Bs + (w * 48 + j * 16 + fr) * 64 + sl);
                acc[j] = __builtin_amdgcn_mfma_f32_16x16x32_bf16(af, bfrag, acc[j], 0, 0, 0);
            }
        }
    }

    #pragma unroll
    for (int j = 0; j < 3; ++j) {
        const int n = w * 48 + j * 16 + fr;
        const float bv = pwb[n];
        const int row0 = (lane >> 4) << 2;
        #pragma unroll
        for (int ii = 0; ii < 4; ++ii)
            offb[(size_t)(m0 + row0 + ii) * HR_ + n] = f2bf(acc[j][ii] + bv);
    }
}

// ---------------------------------------------------------------------------
// Fused banded-score + softmax + band coefficients + PV.
// ---------------------------------------------------------------------------
__global__ __launch_bounds__(256) void coeff_pv_kernel(const unsigned short* __restrict__ qkv,
                                                       const unsigned short* __restrict__ offb,
                                                       const float* __restrict__ rel_scale_p,
                                                       unsigned short* __restrict__ attb) {
    __shared__ __align__(16) float S[4][16][33];
    __shared__ __align__(16) float C[4][16][32];
    const int tid  = threadIdx.x;
    const int w    = tid >> 6, lane = tid & 63;
    const int tile = blockIdx.x * 4 + w;
    const int t0   = (tile & 127) << 4;
    const int h    = (tile >> 7) & 15;
    const int b    = tile >> 11;
    const int fr   = lane & 15;
    const int fo   = (lane >> 4) << 3;

    const unsigned short* qrow = qkv + (size_t)(b * Q_ + t0 + fr) * NQKV + h * DH_ + fo;
    const bf16x8 af0 = *(const bf16x8*)qrow;
    const bf16x8 af1 = *(const bf16x8*)(qrow + 32);

    f32x4 acc0 = (f32x4){0.f, 0.f, 0.f, 0.f};
    f32x4 acc1 = acc0;
    {
        int j = min(max(t0 - 8 + fr, 0), Q_ - 1);
        const unsigned short* krow = qkv + (size_t)(b * Q_ + j) * NQKV + D_ + h * DH_ + fo;
        acc0 = __builtin_amdgcn_mfma_f32_16x16x32_bf16(af0, *(const bf16x8*)krow, acc0, 0, 0, 0);
        acc0 = __builtin_amdgcn_mfma_f32_16x16x32_bf16(af1, *(const bf16x8*)(krow + 32), acc0, 0, 0, 0);
    }
    {
        int j = min(max(t0 + 8 + fr, 0), Q_ - 1);
        const unsigned short* krow = qkv + (size_t)(b * Q_ + j) * NQKV + D_ + h * DH_ + fo;
        acc1 = __builtin_amdgcn_mfma_f32_16x16x32_bf16(af0, *(const bf16x8*)krow, acc1, 0, 0, 0);
        acc1 = __builtin_amdgcn_mfma_f32_16x16x32_bf16(af1, *(const bf16x8*)(krow + 32), acc1, 0, 0, 0);
    }

    float vj[32];
    {
        const unsigned short* vb = qkv + (size_t)b * Q_ * NQKV + 2 * D_ + h * DH_ + lane;
        #pragma unroll
        for (int i2 = 0; i2 < 32; ++i2) {
            const int j = min(max(t0 - 8 + i2, 0), Q_ - 1);
            vj[i2] = bf2f(vb[(size_t)j * NQKV]);
        }
    }

    const int row0 = (lane >> 4) << 2;
    #pragma unroll
    for (int ii = 0; ii < 4; ++ii) {
        S[w][row0 + ii][fr]      = acc0[ii];
        S[w][row0 + ii][16 + fr] = acc1[ii];
    }
    {
        const int tr = lane >> 2, cg = (lane & 3) << 3;
        #pragma unroll
        for (int k = 0; k < 8; ++k) C[w][tr][cg + k] = 0.f;
    }
    __syncthreads();

    const int tloc = lane & 15;
    const int rs   = lane >> 4;
    const int t    = t0 + tloc;
    const float rel_scale = rel_scale_p[0];
    const unsigned short* offrow = offb + (size_t)(b * Q_ + t) * HR_ + h * R_;

    float sc[3], fr3[3];
    int   cl[3], ch[3];
    #pragma unroll
    for (int i = 0; i < 3; ++i) {
        const int r = rs * 3 + i;
        const float off    = bf2f(offrow[r]);
        const float anchor = -2.0f + (4.0f / 11.0f) * (float)r;
        float pos = (float)t + anchor + 6.0f * tanhf(off);
        pos = fminf(fmaxf(pos, 0.0f), (float)(Q_ - 1));
        const float fl = floorf(pos);
        const int lo = (int)fl;
        const int hi = (int)ceilf(pos);
        const float f = pos - fl;
        cl[i] = lo - t0 + 8;
        ch[i] = hi - t0 + 8;
        fr3[i] = f;
        const float slo = S[w][tloc][cl[i]];
        const float shi = S[w][tloc][ch[i]];
        sc[i] = (slo * (1.0f - f) + shi * f) * 0.125f - rel_scale * fabsf(pos - (float)t);
    }

    float mx = fmaxf(fmaxf(sc[0], sc[1]), sc[2]);
    mx = fmaxf(mx, __shfl_xor(mx, 16));
    mx = fmaxf(mx, __shfl_xor(mx, 32));
    float e[3];
    #pragma unroll
    for (int i = 0; i < 3; ++i) e[i] = expf(sc[i] - mx);
    float sum = e[0] + e[1] + e[2];
    sum += __shfl_xor(sum, 16);
    sum += __shfl_xor(sum, 32);
    const float inv = 1.0f / sum;

    #pragma unroll
    for (int i = 0; i < 3; ++i) {
        const float wgt = e[i] * inv;
        atomicAdd(&C[w][tloc][cl[i]], wgt * (1.0f - fr3[i]));
        atomicAdd(&C[w][tloc][ch[i]], wgt * fr3[i]);
    }
    __syncthreads();

    #pragma unroll
    for (int tl = 0; tl < 16; ++tl) {
        const int st = tl & ~3;
        float cw[20];
        #pragma unroll
        for (int q2 = 0; q2 < 5; ++q2)
            *(f32x4*)&cw[q2 * 4] = *(const f32x4*)&C[w][tl][st + q2 * 4];
        float acc2 = 0.f;
        #pragma unroll
        for (int k = 0; k <= 16; ++k)
            acc2 = fmaf(cw[tl - st + k], vj[tl + k], acc2);
        attb[(size_t)(b * Q_ + t0 + tl) * D_ + h * DH_ + lane] = f2bf(acc2);
    }
}

// ---------------------------------------------------------------------------
// Launch
// ---------------------------------------------------------------------------
extern "C" void kernel_launch(void* const* d_in, const int* in_sizes, int n_in,
                              void* d_out, int out_size, void* d_ws, size_t ws_size,
                              hipStream_t stream) {
    const float* x    = (const float*)d_in[0];
    const float* wq   = (const float*)d_in[1];
    const float* bq   = (const float*)d_in[2];
    const float* wk   = (const float*)d_in[3];
    const float* bk   = (const float*)d_in[4];
    const float* wv   = (const float*)d_in[5];
    const float* bv   = (const float*)d_in[6];
    const float* wo   = (const float*)d_in[7];
    const float* bo   = (const float*)d_in[8];
    const float* dww  = (const float*)d_in[9];
    const float* dwb  = (const float*)d_in[10];
    const float* pww  = (const float*)d_in[11];
    const float* pwb  = (const float*)d_in[12];
    const float* rsc  = (const float*)d_in[13];
    float* out = (float*)d_out;

    unsigned short* xb   = (unsigned short*)d_ws;              // M_*D_
    unsigned short* wqkv = xb   + (size_t)M_ * D_;             // NQKV*D_
    unsigned short* wob  = wqkv + (size_t)NQKV * D_;           // D_*D_
    unsigned short* pwwb = wob  + (size_t)D_ * D_;             // HR_*D_
    unsigned short* qkv  = pwwb + (size_t)HR_ * D_;            // M_*NQKV
    unsigned short* offb = qkv  + (size_t)M_ * NQKV;           // M_*HR_
    unsigned short* attb = offb + (size_t)M_ * HR_;            // M_*D_
    float*          bqkv = (float*)(attb + (size_t)M_ * D_);   // NQKV

    dim3 blk(256);

    hipLaunchKernelGGL(cvt_all, dim3(4204), blk, 0, stream,
                       x, wq, wk, wv, wo, pww, bq, bk, bv, xb, wqkv, wob, pwwb, bqkv);

    // fused QKV projection: (4096 x 1024) @ (3072 x 1024)^T, 768 blocks
    hipLaunchKernelGGL((gemm_mfma<128, true>), dim3(NQKV / 128, M_ / 128), blk, 0, stream,
                       xb, wqkv, bqkv, qkv, M_, NQKV, D_);

    // fused depthwise conv + gelu + pointwise conv -> raw offsets
    hipLaunchKernelGGL(dwpw_kernel, dim3(M_ / 16), blk, 0, stream,
                       qkv, dww, dwb, pwwb, pwb, offb);

    // banded score + softmax + coefficients + PV (fused)
    hipLaunchKernelGGL(coeff_pv_kernel, dim3(B_ * H_ * (Q_ / 16) / 4), blk, 0, stream,
                       qkv, offb, rsc, attb);

    // output projection -> fp32 d_out (512 blocks)
    hipLaunchKernelGGL((gemm_mfma<64, false>), dim3(D_ / 64, M_ / 128), blk, 0, stream,
                       attb, wob, bo, out, M_, D_, D_);
}